// Round 2
// baseline (293.530 us; speedup 1.0000x reference)
//
#include <hip/hip_runtime.h>
#include <hip/hip_bf16.h>

#define DIM_IN  128
#define DIM_OUT 64

static inline size_t align256(size_t x) { return (x + 255) & ~(size_t)255; }

// ---------------------------------------------------------------------------
// K1: h = x @ W. 8 rows per wave, lane = output column.
// W staged in LDS [k][col] (conflict-free: 64 consecutive floats = 2/bank).
// One ds_read of W feeds 8 FMAs; x rows read via wave-uniform float4 loads
// (readfirstlane'd wave id -> scalar address -> s_load path).
// ---------------------------------------------------------------------------
__global__ __launch_bounds__(256) void gnn_gemm_kernel(
    const float* __restrict__ x, const float* __restrict__ W,
    float* __restrict__ h, int n_nodes)
{
    __shared__ float Ws[DIM_IN * DIM_OUT];  // 32 KiB
    for (int i = threadIdx.x; i < DIM_IN * DIM_OUT; i += 256)
        Ws[i] = W[i];
    __syncthreads();

    const int lane = threadIdx.x & 63;
    const int wv   = __builtin_amdgcn_readfirstlane(threadIdx.x >> 6);
    const int row0 = (blockIdx.x * 4 + wv) * 8;
    if (row0 >= n_nodes) return;

    const float* xp = x + (size_t)row0 * DIM_IN;
    float acc[8] = {0.f, 0.f, 0.f, 0.f, 0.f, 0.f, 0.f, 0.f};
    const int nr = (n_nodes - row0 >= 8) ? 8 : (n_nodes - row0);

    if (nr == 8) {
        for (int k = 0; k < DIM_IN; k += 4) {
            float4 xv[8];
            #pragma unroll
            for (int r = 0; r < 8; ++r)
                xv[r] = *reinterpret_cast<const float4*>(xp + (size_t)r * DIM_IN + k);
            #pragma unroll
            for (int j = 0; j < 4; ++j) {
                const float w = Ws[(k + j) * DIM_OUT + lane];
                #pragma unroll
                for (int r = 0; r < 8; ++r)
                    acc[r] += reinterpret_cast<const float*>(&xv[r])[j] * w;
            }
        }
        #pragma unroll
        for (int r = 0; r < 8; ++r)
            h[(size_t)(row0 + r) * DIM_OUT + lane] = acc[r];
    } else {
        for (int r = 0; r < nr; ++r) {
            float s = 0.f;
            for (int k = 0; k < DIM_IN; ++k)
                s += xp[(size_t)r * DIM_IN + k] * Ws[k * DIM_OUT + lane];
            h[(size_t)(row0 + r) * DIM_OUT + lane] = s;
        }
    }
}

// ---------------------------------------------------------------------------
// K2a: histogram of destination rows (int atomics on 200 KB, L2-resident)
// ---------------------------------------------------------------------------
__global__ __launch_bounds__(256) void gnn_hist_kernel(
    const int* __restrict__ edge_rows, int* __restrict__ counts, int n_edges)
{
    const int e = blockIdx.x * blockDim.x + threadIdx.x;
    if (e < n_edges) atomicAdd(&counts[edge_rows[e]], 1);
}

// ---------------------------------------------------------------------------
// K2b: single-block exclusive scan of counts -> offsets (and cursor copy).
// 1024 threads, 8 elements/thread/chunk, shfl wave-scan + cross-wave scan.
// ---------------------------------------------------------------------------
__global__ __launch_bounds__(1024) void gnn_scan_kernel(
    const int* __restrict__ counts, int* __restrict__ offsets,
    int* __restrict__ cursor, int n)
{
    __shared__ int wsum[16];
    __shared__ int s_carry;
    __shared__ int s_chunk_total;
    const int tid = threadIdx.x;
    const int lane = tid & 63;
    const int wv = tid >> 6;
    if (tid == 0) s_carry = 0;
    __syncthreads();

    for (int base = 0; base < n; base += 8192) {
        const int idx = base + tid * 8;
        int v[8];
        #pragma unroll
        for (int j = 0; j < 8; ++j) {
            const int k = idx + j;
            v[j] = (k < n) ? counts[k] : 0;
        }
        #pragma unroll
        for (int j = 1; j < 8; ++j) v[j] += v[j - 1];
        const int ts = v[7];

        // wave-level inclusive scan of per-thread sums
        int incl = ts;
        #pragma unroll
        for (int off = 1; off < 64; off <<= 1) {
            const int t = __shfl_up(incl, off);
            if (lane >= off) incl += t;
        }
        if (lane == 63) wsum[wv] = incl;
        __syncthreads();

        if (wv == 0) {
            const int val = (lane < 16) ? wsum[lane] : 0;
            int wincl = val;
            #pragma unroll
            for (int off = 1; off < 16; off <<= 1) {
                const int t = __shfl_up(wincl, off);
                if (lane >= off) wincl += t;
            }
            if (lane < 16) wsum[lane] = wincl - val;  // exclusive wave prefix
            if (lane == 15) s_chunk_total = wincl;
        }
        __syncthreads();

        const int excl_thread = (incl - ts) + wsum[wv];
        const int b = s_carry + excl_thread;
        #pragma unroll
        for (int j = 0; j < 8; ++j) {
            const int k = idx + j;
            if (k < n) {
                const int o = b + (j ? v[j - 1] : 0);
                offsets[k] = o;
                cursor[k]  = o;
            }
        }
        __syncthreads();  // all reads of s_carry done
        if (tid == 0) s_carry += s_chunk_total;
        __syncthreads();
    }
}

// ---------------------------------------------------------------------------
// K2c: scatter edges into row-sorted (col, val) pairs
// ---------------------------------------------------------------------------
__global__ __launch_bounds__(256) void gnn_scatter_pairs_kernel(
    const int* __restrict__ edge_rows, const int* __restrict__ edge_cols,
    const float* __restrict__ adj_vals, int* __restrict__ cursor,
    int2* __restrict__ pairs, int n_edges)
{
    const int e = blockIdx.x * blockDim.x + threadIdx.x;
    if (e >= n_edges) return;
    const int r = edge_rows[e];
    const int pos = atomicAdd(&cursor[r], 1);
    pairs[pos] = make_int2(edge_cols[e], __float_as_int(adj_vals[e]));
}

// ---------------------------------------------------------------------------
// K3: segmented reduction. One wave per output row, lane = dim.
// Edge (col,val) pairs loaded coalesced then shfl-broadcast; h gathers are
// fully-coalesced 256 B rows. Zero atomics.
// ---------------------------------------------------------------------------
__global__ __launch_bounds__(256) void gnn_reduce_kernel(
    const float* __restrict__ h, const int* __restrict__ offsets,
    const int* __restrict__ counts, const int2* __restrict__ pairs,
    float* __restrict__ out, int n_nodes)
{
    const int lane = threadIdx.x & 63;
    const int row = blockIdx.x * 4 + (threadIdx.x >> 6);
    if (row >= n_nodes) return;

    const int start = offsets[row];
    const int cnt   = counts[row];
    float sum = 0.f;

    for (int base = 0; base < cnt; base += 64) {
        const int m = (cnt - base >= 64) ? 64 : (cnt - base);
        int2 pr = make_int2(0, 0);
        if (lane < m) pr = pairs[start + base + lane];
        for (int i = 0; i < m; ++i) {
            const int   c = __shfl(pr.x, i);
            const float a = __int_as_float(__shfl(pr.y, i));
            sum += a * h[(size_t)c * DIM_OUT + lane];
        }
    }
    out[(size_t)row * DIM_OUT + lane] = sum;
}

// ---------------------------------------------------------------------------
// Fallback scatter (round-1 path) if ws_size is too small for the sort.
// ---------------------------------------------------------------------------
__global__ __launch_bounds__(256) void gnn_scatter_atomic_kernel(
    const float* __restrict__ h, const int* __restrict__ edge_rows,
    const int* __restrict__ edge_cols, const float* __restrict__ adj_vals,
    float* __restrict__ out, int n_edges)
{
    const long long idx = (long long)blockIdx.x * blockDim.x + threadIdx.x;
    if (idx >= (long long)n_edges * DIM_OUT) return;
    const int e = (int)(idx >> 6);
    const int d = (int)(idx & 63);
    const float v = adj_vals[e] * h[(size_t)edge_cols[e] * DIM_OUT + d];
    atomicAdd(&out[(size_t)edge_rows[e] * DIM_OUT + d], v);
}

extern "C" void kernel_launch(void* const* d_in, const int* in_sizes, int n_in,
                              void* d_out, int out_size, void* d_ws, size_t ws_size,
                              hipStream_t stream)
{
    const float* x         = (const float*)d_in[0];
    const float* W         = (const float*)d_in[1];
    const int*   edge_rows = (const int*)d_in[2];
    const int*   edge_cols = (const int*)d_in[3];
    const float* adj_vals  = (const float*)d_in[4];
    float*       out       = (float*)d_out;

    const int n_nodes = in_sizes[0] / DIM_IN;
    const int n_edges = in_sizes[2];

    // workspace layout
    char* ws = (char*)d_ws;
    size_t off = 0;
    float* h = (float*)(ws + off);            off = align256(off + (size_t)n_nodes * DIM_OUT * 4);
    int* counts = (int*)(ws + off);           off = align256(off + (size_t)n_nodes * 4);
    int* offsets = (int*)(ws + off);          off = align256(off + (size_t)n_nodes * 4);
    int* cursor = (int*)(ws + off);           off = align256(off + (size_t)n_nodes * 4);
    int2* pairs = (int2*)(ws + off);          off = align256(off + (size_t)n_edges * 8);
    const bool use_sort = (off <= ws_size);

    // K1: dense transform (8 rows/wave)
    {
        const int rows_per_block = 32;  // 4 waves x 8 rows
        const int grid = (n_nodes + rows_per_block - 1) / rows_per_block;
        gnn_gemm_kernel<<<grid, 256, 0, stream>>>(x, W, h, n_nodes);
    }

    if (use_sort) {
        hipMemsetAsync(counts, 0, (size_t)n_nodes * 4, stream);
        {
            const int grid = (n_edges + 255) / 256;
            gnn_hist_kernel<<<grid, 256, 0, stream>>>(edge_rows, counts, n_edges);
        }
        gnn_scan_kernel<<<1, 1024, 0, stream>>>(counts, offsets, cursor, n_nodes);
        {
            const int grid = (n_edges + 255) / 256;
            gnn_scatter_pairs_kernel<<<grid, 256, 0, stream>>>(
                edge_rows, edge_cols, adj_vals, cursor, pairs, n_edges);
        }
        {
            const int grid = (n_nodes + 3) / 4;  // 4 rows (waves) per block
            gnn_reduce_kernel<<<grid, 256, 0, stream>>>(
                h, offsets, counts, pairs, out, n_nodes);
        }
    } else {
        hipMemsetAsync(d_out, 0, (size_t)out_size * sizeof(float), stream);
        const long long total = (long long)n_edges * DIM_OUT;
        const int grid = (int)((total + 255) / 256);
        gnn_scatter_atomic_kernel<<<grid, 256, 0, stream>>>(
            h, edge_rows, edge_cols, adj_vals, out, n_edges);
    }
}

// Round 3
// 258.557 us; speedup vs baseline: 1.1353x; 1.1353x over previous
//
#include <hip/hip_runtime.h>
#include <hip/hip_bf16.h>

#define DIM_IN  128
#define DIM_OUT 64

static inline size_t align256(size_t x) { return (x + 255) & ~(size_t)255; }

// ---------------------------------------------------------------------------
// K1: h_bf16 = bf16(x @ W). One wave per 16 rows, lane = output column.
// W column kept in 128 VGPRs (coalesced load, L1-hot after first wave).
// x rows read as wave-uniform float4 broadcasts (1 request / wave / 16B).
// 4-row groups give 4 independent FMA chains (dep distance 8cyc > 4cyc lat).
// No LDS -> occupancy limited only by VGPRs (~3 waves/SIMD).
// ---------------------------------------------------------------------------
__global__ __launch_bounds__(256) void gnn_gemm_kernel(
    const float* __restrict__ x, const float* __restrict__ W,
    __hip_bfloat16* __restrict__ hb, int n_nodes)
{
    const int lane = threadIdx.x & 63;
    const int wv   = __builtin_amdgcn_readfirstlane(threadIdx.x >> 6);
    const int row0 = (blockIdx.x * 4 + wv) * 16;
    if (row0 >= n_nodes) return;

    // W[:, lane] -> 128 VGPRs. Coalesced (64 consecutive floats per k).
    float wreg[DIM_IN];
    #pragma unroll
    for (int k = 0; k < DIM_IN; ++k)
        wreg[k] = W[k * DIM_OUT + lane];

    const int rows = (n_nodes - row0 >= 16) ? 16 : (n_nodes - row0);

    int rg = 0;
    for (; rg + 4 <= rows; rg += 4) {
        const float* xp = x + (size_t)(row0 + rg) * DIM_IN;
        float a0 = 0.f, a1 = 0.f, a2 = 0.f, a3 = 0.f;
        #pragma unroll
        for (int kk = 0; kk < DIM_IN / 4; ++kk) {
            const float4 x0 = *reinterpret_cast<const float4*>(xp + 0 * DIM_IN + kk * 4);
            const float4 x1 = *reinterpret_cast<const float4*>(xp + 1 * DIM_IN + kk * 4);
            const float4 x2 = *reinterpret_cast<const float4*>(xp + 2 * DIM_IN + kk * 4);
            const float4 x3 = *reinterpret_cast<const float4*>(xp + 3 * DIM_IN + kk * 4);
            a0 += x0.x * wreg[kk * 4 + 0]; a1 += x1.x * wreg[kk * 4 + 0];
            a2 += x2.x * wreg[kk * 4 + 0]; a3 += x3.x * wreg[kk * 4 + 0];
            a0 += x0.y * wreg[kk * 4 + 1]; a1 += x1.y * wreg[kk * 4 + 1];
            a2 += x2.y * wreg[kk * 4 + 1]; a3 += x3.y * wreg[kk * 4 + 1];
            a0 += x0.z * wreg[kk * 4 + 2]; a1 += x1.z * wreg[kk * 4 + 2];
            a2 += x2.z * wreg[kk * 4 + 2]; a3 += x3.z * wreg[kk * 4 + 2];
            a0 += x0.w * wreg[kk * 4 + 3]; a1 += x1.w * wreg[kk * 4 + 3];
            a2 += x2.w * wreg[kk * 4 + 3]; a3 += x3.w * wreg[kk * 4 + 3];
        }
        const size_t ob = (size_t)(row0 + rg) * DIM_OUT + lane;
        hb[ob + 0 * DIM_OUT] = __float2bfloat16(a0);
        hb[ob + 1 * DIM_OUT] = __float2bfloat16(a1);
        hb[ob + 2 * DIM_OUT] = __float2bfloat16(a2);
        hb[ob + 3 * DIM_OUT] = __float2bfloat16(a3);
    }
    for (; rg < rows; ++rg) {
        const float* xp = x + (size_t)(row0 + rg) * DIM_IN;
        float a = 0.f;
        #pragma unroll
        for (int k = 0; k < DIM_IN; ++k)
            a += xp[k] * wreg[k];
        hb[(size_t)(row0 + rg) * DIM_OUT + lane] = __float2bfloat16(a);
    }
}

// ---------------------------------------------------------------------------
// K2a: histogram of destination rows (int atomics on 200 KB, L2-resident)
// ---------------------------------------------------------------------------
__global__ __launch_bounds__(256) void gnn_hist_kernel(
    const int* __restrict__ edge_rows, int* __restrict__ counts, int n_edges)
{
    const int e = blockIdx.x * blockDim.x + threadIdx.x;
    if (e < n_edges) atomicAdd(&counts[edge_rows[e]], 1);
}

// ---------------------------------------------------------------------------
// K2b: single-block exclusive scan of counts -> offsets (and cursor copy).
// ---------------------------------------------------------------------------
__global__ __launch_bounds__(1024) void gnn_scan_kernel(
    const int* __restrict__ counts, int* __restrict__ offsets,
    int* __restrict__ cursor, int n)
{
    __shared__ int wsum[16];
    __shared__ int s_carry;
    __shared__ int s_chunk_total;
    const int tid = threadIdx.x;
    const int lane = tid & 63;
    const int wv = tid >> 6;
    if (tid == 0) s_carry = 0;
    __syncthreads();

    for (int base = 0; base < n; base += 8192) {
        const int idx = base + tid * 8;
        int v[8];
        #pragma unroll
        for (int j = 0; j < 8; ++j) {
            const int k = idx + j;
            v[j] = (k < n) ? counts[k] : 0;
        }
        #pragma unroll
        for (int j = 1; j < 8; ++j) v[j] += v[j - 1];
        const int ts = v[7];

        int incl = ts;
        #pragma unroll
        for (int off = 1; off < 64; off <<= 1) {
            const int t = __shfl_up(incl, off);
            if (lane >= off) incl += t;
        }
        if (lane == 63) wsum[wv] = incl;
        __syncthreads();

        if (wv == 0) {
            const int val = (lane < 16) ? wsum[lane] : 0;
            int wincl = val;
            #pragma unroll
            for (int off = 1; off < 16; off <<= 1) {
                const int t = __shfl_up(wincl, off);
                if (lane >= off) wincl += t;
            }
            if (lane < 16) wsum[lane] = wincl - val;
            if (lane == 15) s_chunk_total = wincl;
        }
        __syncthreads();

        const int excl_thread = (incl - ts) + wsum[wv];
        const int b = s_carry + excl_thread;
        #pragma unroll
        for (int j = 0; j < 8; ++j) {
            const int k = idx + j;
            if (k < n) {
                const int o = b + (j ? v[j - 1] : 0);
                offsets[k] = o;
                cursor[k]  = o;
            }
        }
        __syncthreads();
        if (tid == 0) s_carry += s_chunk_total;
        __syncthreads();
    }
}

// ---------------------------------------------------------------------------
// K2c: scatter edges into row-sorted (col, val) pairs
// ---------------------------------------------------------------------------
__global__ __launch_bounds__(256) void gnn_scatter_pairs_kernel(
    const int* __restrict__ edge_rows, const int* __restrict__ edge_cols,
    const float* __restrict__ adj_vals, int* __restrict__ cursor,
    int2* __restrict__ pairs, int n_edges)
{
    const int e = blockIdx.x * blockDim.x + threadIdx.x;
    if (e >= n_edges) return;
    const int r = edge_rows[e];
    const int pos = atomicAdd(&cursor[r], 1);
    pairs[pos] = make_int2(edge_cols[e], __float_as_int(adj_vals[e]));
}

// ---------------------------------------------------------------------------
// K3: segmented reduction over row-sorted pairs. Wave per row, lane = dim.
// h gathered as bf16 (128 B/edge instead of 256 B; 6.4 MB table -> better
// L2 residency). 2-edge unroll, independent accumulators.
// ---------------------------------------------------------------------------
__global__ __launch_bounds__(256) void gnn_reduce_kernel(
    const __hip_bfloat16* __restrict__ hb, const int* __restrict__ offsets,
    const int* __restrict__ counts, const int2* __restrict__ pairs,
    float* __restrict__ out, int n_nodes)
{
    const int lane = threadIdx.x & 63;
    const int row = blockIdx.x * 4 + (threadIdx.x >> 6);
    if (row >= n_nodes) return;

    const int start = offsets[row];
    const int cnt   = counts[row];
    float s0 = 0.f, s1 = 0.f;

    for (int base = 0; base < cnt; base += 64) {
        const int m = (cnt - base >= 64) ? 64 : (cnt - base);
        int2 pr = make_int2(0, 0);
        if (lane < m) pr = pairs[start + base + lane];
        int i = 0;
        for (; i + 2 <= m; i += 2) {
            const int   c0 = __shfl(pr.x, i);
            const int   c1 = __shfl(pr.x, i + 1);
            const float a0 = __int_as_float(__shfl(pr.y, i));
            const float a1 = __int_as_float(__shfl(pr.y, i + 1));
            s0 += a0 * __bfloat162float(hb[(size_t)c0 * DIM_OUT + lane]);
            s1 += a1 * __bfloat162float(hb[(size_t)c1 * DIM_OUT + lane]);
        }
        if (i < m) {
            const int   c = __shfl(pr.x, i);
            const float a = __int_as_float(__shfl(pr.y, i));
            s0 += a * __bfloat162float(hb[(size_t)c * DIM_OUT + lane]);
        }
    }
    out[(size_t)row * DIM_OUT + lane] = s0 + s1;
}

// ---------------------------------------------------------------------------
// Fallback scatter (atomics) if ws_size too small for the sort path.
// ---------------------------------------------------------------------------
__global__ __launch_bounds__(256) void gnn_scatter_atomic_kernel(
    const __hip_bfloat16* __restrict__ hb, const int* __restrict__ edge_rows,
    const int* __restrict__ edge_cols, const float* __restrict__ adj_vals,
    float* __restrict__ out, int n_edges)
{
    const long long idx = (long long)blockIdx.x * blockDim.x + threadIdx.x;
    if (idx >= (long long)n_edges * DIM_OUT) return;
    const int e = (int)(idx >> 6);
    const int d = (int)(idx & 63);
    const float v = adj_vals[e] *
        __bfloat162float(hb[(size_t)edge_cols[e] * DIM_OUT + d]);
    atomicAdd(&out[(size_t)edge_rows[e] * DIM_OUT + d], v);
}

extern "C" void kernel_launch(void* const* d_in, const int* in_sizes, int n_in,
                              void* d_out, int out_size, void* d_ws, size_t ws_size,
                              hipStream_t stream)
{
    const float* x         = (const float*)d_in[0];
    const float* W         = (const float*)d_in[1];
    const int*   edge_rows = (const int*)d_in[2];
    const int*   edge_cols = (const int*)d_in[3];
    const float* adj_vals  = (const float*)d_in[4];
    float*       out       = (float*)d_out;

    const int n_nodes = in_sizes[0] / DIM_IN;
    const int n_edges = in_sizes[2];

    // workspace layout
    char* ws = (char*)d_ws;
    size_t off = 0;
    __hip_bfloat16* hb = (__hip_bfloat16*)(ws + off);
    off = align256(off + (size_t)n_nodes * DIM_OUT * 2);          // 6.4 MB
    int* counts  = (int*)(ws + off); off = align256(off + (size_t)n_nodes * 4);
    int* offsets = (int*)(ws + off); off = align256(off + (size_t)n_nodes * 4);
    int* cursor  = (int*)(ws + off); off = align256(off + (size_t)n_nodes * 4);
    int2* pairs  = (int2*)(ws + off); off = align256(off + (size_t)n_edges * 8);
    const bool use_sort = (off <= ws_size);

    // K1: dense transform, 16 rows/wave, 4 waves/block
    {
        const int rows_per_block = 64;
        const int grid = (n_nodes + rows_per_block - 1) / rows_per_block;
        gnn_gemm_kernel<<<grid, 256, 0, stream>>>(x, W, hb, n_nodes);
    }

    if (use_sort) {
        hipMemsetAsync(counts, 0, (size_t)n_nodes * 4, stream);
        gnn_hist_kernel<<<(n_edges + 255) / 256, 256, 0, stream>>>(
            edge_rows, counts, n_edges);
        gnn_scan_kernel<<<1, 1024, 0, stream>>>(counts, offsets, cursor, n_nodes);
        gnn_scatter_pairs_kernel<<<(n_edges + 255) / 256, 256, 0, stream>>>(
            edge_rows, edge_cols, adj_vals, cursor, pairs, n_edges);
        gnn_reduce_kernel<<<(n_nodes + 3) / 4, 256, 0, stream>>>(
            hb, offsets, counts, pairs, out, n_nodes);
    } else {
        hipMemsetAsync(d_out, 0, (size_t)out_size * sizeof(float), stream);
        const long long total = (long long)n_edges * DIM_OUT;
        gnn_scatter_atomic_kernel<<<(int)((total + 255) / 256), 256, 0, stream>>>(
            hb, edge_rows, edge_cols, adj_vals, out, n_edges);
    }
}

// Round 4
// 229.153 us; speedup vs baseline: 1.2809x; 1.1283x over previous
//
#include <hip/hip_runtime.h>
#include <hip/hip_bf16.h>

#define DIM_IN  128
#define DIM_OUT 64
#define EPW     128   // edges per wave-chunk in the segmented reduce

typedef __attribute__((ext_vector_type(8))) short bf16x8;
typedef __attribute__((ext_vector_type(4))) float f32x4;

static inline size_t align256(size_t x) { return (x + 255) & ~(size_t)255; }

static __device__ inline short f2bs(float f) {
    __hip_bfloat16 b = __float2bfloat16(f);
    return *reinterpret_cast<short*>(&b);
}

// ---------------------------------------------------------------------------
// K1: hb = bf16(x @ W) via MFMA 16x16x32 bf16. One wave per 16-row tile.
// Fragment mapping (guide §3, m89/m92 verified):
//   A: row = lane&15, k = (lane>>4)*8 + i   (8 contiguous k per lane)
//   B: col = lane&15, k = (lane>>4)*8 + i
//   D: col = lane&15, row = (lane>>4)*4 + r
// W fragments (4 ksteps x 4 ntiles, 64 VGPR) loaded per wave from L2-hot W.
// ---------------------------------------------------------------------------
__global__ __launch_bounds__(256) void gnn_gemm_mfma_kernel(
    const float* __restrict__ x, const float* __restrict__ W,
    __hip_bfloat16* __restrict__ hb, int n_nodes)
{
    const int lane = threadIdx.x & 63;
    const int wid  = blockIdx.x * 4 + (threadIdx.x >> 6);
    const int ntile_rows = (n_nodes + 15) >> 4;
    if (wid >= ntile_rows) return;

    const int g   = lane >> 4;   // k-octet group (0..3)
    const int l16 = lane & 15;

    // ---- A loads first (HBM, long latency): 16 rows x 128 k, 32B/lane/kstep
    const int row = wid * 16 + l16;
    const int arow = (row < n_nodes) ? row : (n_nodes - 1);
    const float* xr = x + (size_t)arow * DIM_IN + g * 8;
    float4 a_lo[4], a_hi[4];
    #pragma unroll
    for (int ks = 0; ks < 4; ++ks) {
        a_lo[ks] = *reinterpret_cast<const float4*>(xr + ks * 32);
        a_hi[ks] = *reinterpret_cast<const float4*>(xr + ks * 32 + 4);
    }

    // ---- B fragments from W (L2-hot after first waves)
    bf16x8 bfrag[4][4];
    #pragma unroll
    for (int ks = 0; ks < 4; ++ks) {
        #pragma unroll
        for (int nt = 0; nt < 4; ++nt) {
            const float* wp = W + (size_t)(ks * 32 + g * 8) * DIM_OUT + nt * 16 + l16;
            bf16x8 f;
            #pragma unroll
            for (int i = 0; i < 8; ++i)
                f[i] = f2bs(wp[(size_t)i * DIM_OUT]);
            bfrag[ks][nt] = f;
        }
    }

    // ---- convert A to bf16 fragments
    bf16x8 afrag[4];
    #pragma unroll
    for (int ks = 0; ks < 4; ++ks) {
        bf16x8 f;
        f[0] = f2bs(a_lo[ks].x); f[1] = f2bs(a_lo[ks].y);
        f[2] = f2bs(a_lo[ks].z); f[3] = f2bs(a_lo[ks].w);
        f[4] = f2bs(a_hi[ks].x); f[5] = f2bs(a_hi[ks].y);
        f[6] = f2bs(a_hi[ks].z); f[7] = f2bs(a_hi[ks].w);
        afrag[ks] = f;
    }

    // ---- 16 MFMAs: 4 ksteps x 4 ntiles, K-accumulate into same acc (guide)
    f32x4 acc[4] = {{0,0,0,0},{0,0,0,0},{0,0,0,0},{0,0,0,0}};
    #pragma unroll
    for (int ks = 0; ks < 4; ++ks) {
        #pragma unroll
        for (int nt = 0; nt < 4; ++nt)
            acc[nt] = __builtin_amdgcn_mfma_f32_16x16x32_bf16(
                afrag[ks], bfrag[ks][nt], acc[nt], 0, 0, 0);
    }

    // ---- store: D col = lane&15, row = g*4 + r
    #pragma unroll
    for (int nt = 0; nt < 4; ++nt) {
        #pragma unroll
        for (int r = 0; r < 4; ++r) {
            const int orow = wid * 16 + g * 4 + r;
            if (orow < n_nodes)
                hb[(size_t)orow * DIM_OUT + nt * 16 + l16] =
                    __float2bfloat16(acc[nt][r]);
        }
    }
}

// ---------------------------------------------------------------------------
// K2a: histogram of destination rows (int atomics, L2-resident)
// ---------------------------------------------------------------------------
__global__ __launch_bounds__(256) void gnn_hist_kernel(
    const int* __restrict__ edge_rows, int* __restrict__ counts, int n_edges)
{
    const int e = blockIdx.x * blockDim.x + threadIdx.x;
    if (e < n_edges) atomicAdd(&counts[edge_rows[e]], 1);
}

// ---------------------------------------------------------------------------
// K2b: single-block exclusive scan of counts -> offsets[n+1] (+ cursor copy)
// ---------------------------------------------------------------------------
__global__ __launch_bounds__(1024) void gnn_scan_kernel(
    const int* __restrict__ counts, int* __restrict__ offsets,
    int* __restrict__ cursor, int n)
{
    __shared__ int wsum[16];
    __shared__ int s_carry;
    __shared__ int s_chunk_total;
    const int tid = threadIdx.x;
    const int lane = tid & 63;
    const int wv = tid >> 6;
    if (tid == 0) s_carry = 0;
    __syncthreads();

    for (int base = 0; base < n; base += 8192) {
        const int idx = base + tid * 8;
        int v[8];
        #pragma unroll
        for (int j = 0; j < 8; ++j) {
            const int k = idx + j;
            v[j] = (k < n) ? counts[k] : 0;
        }
        #pragma unroll
        for (int j = 1; j < 8; ++j) v[j] += v[j - 1];
        const int ts = v[7];

        int incl = ts;
        #pragma unroll
        for (int off = 1; off < 64; off <<= 1) {
            const int t = __shfl_up(incl, off);
            if (lane >= off) incl += t;
        }
        if (lane == 63) wsum[wv] = incl;
        __syncthreads();

        if (wv == 0) {
            const int val = (lane < 16) ? wsum[lane] : 0;
            int wincl = val;
            #pragma unroll
            for (int off = 1; off < 16; off <<= 1) {
                const int t = __shfl_up(wincl, off);
                if (lane >= off) wincl += t;
            }
            if (lane < 16) wsum[lane] = wincl - val;
            if (lane == 15) s_chunk_total = wincl;
        }
        __syncthreads();

        const int excl_thread = (incl - ts) + wsum[wv];
        const int b = s_carry + excl_thread;
        #pragma unroll
        for (int j = 0; j < 8; ++j) {
            const int k = idx + j;
            if (k < n) {
                const int o = b + (j ? v[j - 1] : 0);
                offsets[k] = o;
                cursor[k]  = o;
            }
        }
        __syncthreads();
        if (tid == 0) s_carry += s_chunk_total;
        __syncthreads();
    }
    if (tid == 0) offsets[n] = s_carry;  // total = n_edges
}

// ---------------------------------------------------------------------------
// K2c: per-chunk starting row. Chunk c's first row r satisfies
// offsets[r] <= c*EPW < offsets[r+1]; exactly one non-empty row qualifies.
// ---------------------------------------------------------------------------
__global__ __launch_bounds__(256) void gnn_chunk_heads_kernel(
    const int* __restrict__ offsets, int* __restrict__ first_row, int n_nodes)
{
    const int r = blockIdx.x * blockDim.x + threadIdx.x;
    if (r >= n_nodes) return;
    const int lo = offsets[r], hi = offsets[r + 1];
    if (lo == hi) return;
    const int c0 = (lo + EPW - 1) / EPW;
    const int c1 = (hi - 1) / EPW;
    for (int c = c0; c <= c1; ++c) first_row[c] = r;
}

// ---------------------------------------------------------------------------
// K2d: scatter edges into row-sorted (col, val) pairs
// ---------------------------------------------------------------------------
__global__ __launch_bounds__(256) void gnn_scatter_pairs_kernel(
    const int* __restrict__ edge_rows, const int* __restrict__ edge_cols,
    const float* __restrict__ adj_vals, int* __restrict__ cursor,
    int2* __restrict__ pairs, int n_edges)
{
    const int e = blockIdx.x * blockDim.x + threadIdx.x;
    if (e >= n_edges) return;
    const int r = edge_rows[e];
    const int pos = atomicAdd(&cursor[r], 1);
    pairs[pos] = make_int2(edge_cols[e], __float_as_int(adj_vals[e]));
}

// ---------------------------------------------------------------------------
// K3: segmented SpMM reduce over row-sorted pairs. One wave per EPW-edge
// chunk; lanes = 2 edges x 32 dim-pairs. Coalesced 128 B bf16 h-row gathers,
// full lane use regardless of degree. Interior rows: plain float2 store;
// chunk-spanning rows: fp32 atomics (out pre-zeroed).
// ---------------------------------------------------------------------------
__global__ __launch_bounds__(256) void gnn_reduce_kernel(
    const __hip_bfloat16* __restrict__ hb, const int* __restrict__ offsets,
    const int2* __restrict__ pairs, const int* __restrict__ first_row,
    float* __restrict__ out, int n_edges)
{
    const int lane = threadIdx.x & 63;
    const int wid  = blockIdx.x * 4 + (threadIdx.x >> 6);
    const int nchunk = (n_edges + EPW - 1) / EPW;
    if (wid >= nchunk) return;

    const int cs = wid * EPW;
    const int ce = (cs + EPW < n_edges) ? cs + EPW : n_edges;
    const int half  = lane >> 5;   // which of the 2 edges per step
    const int dpair = lane & 31;   // dim pair (2 bf16 = 4 B)

    int r = first_row[wid];
    int pos = cs;
    const unsigned short* hbs = reinterpret_cast<const unsigned short*>(hb);

    while (pos < ce) {
        while (offsets[r + 1] <= pos) ++r;   // skip empty rows (wave-uniform)
        const int se_full = offsets[r + 1];
        const int se = (se_full < ce) ? se_full : ce;

        float acc0 = 0.f, acc1 = 0.f;
        // prefetch first pair
        int idx0 = pos + half;
        int2 pr = pairs[(idx0 < se) ? idx0 : pos];
        for (int p = pos; p < se; p += 2) {
            const int2 cur = pr;
            const bool vcur = (p + half) < se;
            const int pn = p + 2;
            if (pn < se) {
                const int idxn = pn + half;
                pr = pairs[(idxn < se) ? idxn : pn];
            }
            const float a = vcur ? __int_as_float(cur.y) : 0.f;
            const unsigned hv = *reinterpret_cast<const unsigned*>(
                hbs + (size_t)cur.x * DIM_OUT + dpair * 2);
            const float h0 = __uint_as_float(hv << 16);
            const float h1 = __uint_as_float(hv & 0xffff0000u);
            acc0 += a * h0;
            acc1 += a * h1;
        }

        // flush row r: combine the two edge-halves
        const float c0 = acc0 + __shfl(acc0, lane ^ 32);
        const float c1 = acc1 + __shfl(acc1, lane ^ 32);
        const bool spans = (offsets[r] < cs) || (se_full > ce);
        if (lane < 32) {
            float* po = out + (size_t)r * DIM_OUT + dpair * 2;
            if (spans) {
                atomicAdd(po, c0);
                atomicAdd(po + 1, c1);
            } else {
                *reinterpret_cast<float2*>(po) = make_float2(c0, c1);
            }
        }
        pos = se;
    }
}

// ---------------------------------------------------------------------------
// Fallback scatter (atomics) if ws_size too small for the sort path.
// ---------------------------------------------------------------------------
__global__ __launch_bounds__(256) void gnn_scatter_atomic_kernel(
    const __hip_bfloat16* __restrict__ hb, const int* __restrict__ edge_rows,
    const int* __restrict__ edge_cols, const float* __restrict__ adj_vals,
    float* __restrict__ out, int n_edges)
{
    const long long idx = (long long)blockIdx.x * blockDim.x + threadIdx.x;
    if (idx >= (long long)n_edges * DIM_OUT) return;
    const int e = (int)(idx >> 6);
    const int d = (int)(idx & 63);
    const float v = adj_vals[e] *
        __bfloat162float(hb[(size_t)edge_cols[e] * DIM_OUT + d]);
    atomicAdd(&out[(size_t)edge_rows[e] * DIM_OUT + d], v);
}

extern "C" void kernel_launch(void* const* d_in, const int* in_sizes, int n_in,
                              void* d_out, int out_size, void* d_ws, size_t ws_size,
                              hipStream_t stream)
{
    const float* x         = (const float*)d_in[0];
    const float* W         = (const float*)d_in[1];
    const int*   edge_rows = (const int*)d_in[2];
    const int*   edge_cols = (const int*)d_in[3];
    const float* adj_vals  = (const float*)d_in[4];
    float*       out       = (float*)d_out;

    const int n_nodes = in_sizes[0] / DIM_IN;
    const int n_edges = in_sizes[2];
    const int nchunk  = (n_edges + EPW - 1) / EPW;

    // workspace layout
    char* ws = (char*)d_ws;
    size_t off = 0;
    __hip_bfloat16* hb = (__hip_bfloat16*)(ws + off);
    off = align256(off + (size_t)n_nodes * DIM_OUT * 2);             // 6.4 MB
    int* counts    = (int*)(ws + off); off = align256(off + (size_t)n_nodes * 4);
    int* offsets   = (int*)(ws + off); off = align256(off + ((size_t)n_nodes + 1) * 4);
    int* cursor    = (int*)(ws + off); off = align256(off + (size_t)n_nodes * 4);
    int* first_row = (int*)(ws + off); off = align256(off + (size_t)nchunk * 4);
    int2* pairs    = (int2*)(ws + off); off = align256(off + (size_t)n_edges * 8);
    const bool use_sort = (off <= ws_size);

    // K1: MFMA dense transform, one wave per 16-row tile
    {
        const int ntiles = (n_nodes + 15) / 16;
        const int grid = (ntiles + 3) / 4;   // 4 waves/block
        gnn_gemm_mfma_kernel<<<grid, 256, 0, stream>>>(x, W, hb, n_nodes);
    }

    if (use_sort) {
        hipMemsetAsync(counts, 0, (size_t)n_nodes * 4, stream);
        hipMemsetAsync(d_out, 0, (size_t)out_size * sizeof(float), stream);
        gnn_hist_kernel<<<(n_edges + 255) / 256, 256, 0, stream>>>(
            edge_rows, counts, n_edges);
        gnn_scan_kernel<<<1, 1024, 0, stream>>>(counts, offsets, cursor, n_nodes);
        gnn_chunk_heads_kernel<<<(n_nodes + 255) / 256, 256, 0, stream>>>(
            offsets, first_row, n_nodes);
        gnn_scatter_pairs_kernel<<<(n_edges + 255) / 256, 256, 0, stream>>>(
            edge_rows, edge_cols, adj_vals, cursor, pairs, n_edges);
        gnn_reduce_kernel<<<(nchunk + 3) / 4, 256, 0, stream>>>(
            hb, offsets, pairs, first_row, out, n_edges);
    } else {
        hipMemsetAsync(d_out, 0, (size_t)out_size * sizeof(float), stream);
        const long long total = (long long)n_edges * DIM_OUT;
        gnn_scatter_atomic_kernel<<<(int)((total + 255) / 256), 256, 0, stream>>>(
            hb, edge_rows, edge_cols, adj_vals, out, n_edges);
    }
}

// Round 5
// 148.784 us; speedup vs baseline: 1.9729x; 1.5402x over previous
//
#include <hip/hip_runtime.h>
#include <hip/hip_bf16.h>

#define DIM_IN  128
#define DIM_OUT 64
#define EPW     128    // edges per wave-chunk in the segmented reduce
#define SCAN_EPB 2048  // elements per scan1 block (256 thr x 8)

typedef __attribute__((ext_vector_type(8))) short bf16x8;
typedef __attribute__((ext_vector_type(4))) float f32x4;

static inline size_t align256(size_t x) { return (x + 255) & ~(size_t)255; }

static __device__ inline short f2bs(float f) {
    __hip_bfloat16 b = __float2bfloat16(f);
    return *reinterpret_cast<short*>(&b);
}

// ---------------------------------------------------------------------------
// K1: hb = bf16(x @ W) via MFMA 16x16x32 bf16. One wave per 16-row tile.
// (verified round 4: dropped out of top-5)
// ---------------------------------------------------------------------------
__global__ __launch_bounds__(256) void gnn_gemm_mfma_kernel(
    const float* __restrict__ x, const float* __restrict__ W,
    __hip_bfloat16* __restrict__ hb, int n_nodes)
{
    const int lane = threadIdx.x & 63;
    const int wid  = blockIdx.x * 4 + (threadIdx.x >> 6);
    const int ntile_rows = (n_nodes + 15) >> 4;
    if (wid >= ntile_rows) return;

    const int g   = lane >> 4;
    const int l16 = lane & 15;

    const int row = wid * 16 + l16;
    const int arow = (row < n_nodes) ? row : (n_nodes - 1);
    const float* xr = x + (size_t)arow * DIM_IN + g * 8;
    float4 a_lo[4], a_hi[4];
    #pragma unroll
    for (int ks = 0; ks < 4; ++ks) {
        a_lo[ks] = *reinterpret_cast<const float4*>(xr + ks * 32);
        a_hi[ks] = *reinterpret_cast<const float4*>(xr + ks * 32 + 4);
    }

    bf16x8 bfrag[4][4];
    #pragma unroll
    for (int ks = 0; ks < 4; ++ks) {
        #pragma unroll
        for (int nt = 0; nt < 4; ++nt) {
            const float* wp = W + (size_t)(ks * 32 + g * 8) * DIM_OUT + nt * 16 + l16;
            bf16x8 f;
            #pragma unroll
            for (int i = 0; i < 8; ++i)
                f[i] = f2bs(wp[(size_t)i * DIM_OUT]);
            bfrag[ks][nt] = f;
        }
    }

    bf16x8 afrag[4];
    #pragma unroll
    for (int ks = 0; ks < 4; ++ks) {
        bf16x8 f;
        f[0] = f2bs(a_lo[ks].x); f[1] = f2bs(a_lo[ks].y);
        f[2] = f2bs(a_lo[ks].z); f[3] = f2bs(a_lo[ks].w);
        f[4] = f2bs(a_hi[ks].x); f[5] = f2bs(a_hi[ks].y);
        f[6] = f2bs(a_hi[ks].z); f[7] = f2bs(a_hi[ks].w);
        afrag[ks] = f;
    }

    f32x4 acc[4] = {{0,0,0,0},{0,0,0,0},{0,0,0,0},{0,0,0,0}};
    #pragma unroll
    for (int ks = 0; ks < 4; ++ks) {
        #pragma unroll
        for (int nt = 0; nt < 4; ++nt)
            acc[nt] = __builtin_amdgcn_mfma_f32_16x16x32_bf16(
                afrag[ks], bfrag[ks][nt], acc[nt], 0, 0, 0);
    }

    #pragma unroll
    for (int nt = 0; nt < 4; ++nt) {
        #pragma unroll
        for (int r = 0; r < 4; ++r) {
            const int orow = wid * 16 + g * 4 + r;
            if (orow < n_nodes)
                hb[(size_t)orow * DIM_OUT + nt * 16 + l16] =
                    __float2bfloat16(acc[nt][r]);
        }
    }
}

// ---------------------------------------------------------------------------
// K2a: histogram of destination rows (int atomics, L2-resident)
// ---------------------------------------------------------------------------
__global__ __launch_bounds__(256) void gnn_hist_kernel(
    const int* __restrict__ edge_rows, int* __restrict__ counts, int n_edges)
{
    const int e = blockIdx.x * blockDim.x + threadIdx.x;
    if (e < n_edges) atomicAdd(&counts[edge_rows[e]], 1);
}

// ---------------------------------------------------------------------------
// K2b: parallel scan, phase 1. Each block scans SCAN_EPB elements
// (exclusive, block-local) into scanbuf and writes its total to bsums.
// ---------------------------------------------------------------------------
__global__ __launch_bounds__(256) void gnn_scan1_kernel(
    const int* __restrict__ counts, int* __restrict__ scanbuf,
    int* __restrict__ bsums, int n)
{
    __shared__ int wsum[4];
    const int tid = threadIdx.x;
    const int lane = tid & 63;
    const int wv = tid >> 6;
    const int idx = blockIdx.x * SCAN_EPB + tid * 8;

    int v[8];
    #pragma unroll
    for (int j = 0; j < 8; ++j) {
        const int k = idx + j;
        v[j] = (k < n) ? counts[k] : 0;
    }
    #pragma unroll
    for (int j = 1; j < 8; ++j) v[j] += v[j - 1];
    const int ts = v[7];

    int incl = ts;
    #pragma unroll
    for (int off = 1; off < 64; off <<= 1) {
        const int t = __shfl_up(incl, off);
        if (lane >= off) incl += t;
    }
    if (lane == 63) wsum[wv] = incl;
    __syncthreads();

    int wbase = 0;
    for (int w = 0; w < wv; ++w) wbase += wsum[w];

    const int excl = wbase + incl - ts;
    #pragma unroll
    for (int j = 0; j < 8; ++j) {
        const int k = idx + j;
        if (k < n) scanbuf[k] = excl + (j ? v[j - 1] : 0);
    }
    if (tid == 255) bsums[blockIdx.x] = wbase + incl;  // block total
}

// ---------------------------------------------------------------------------
// K2c: phase 2 — exclusive scan of block sums (nb <= 64), one wave.
// ---------------------------------------------------------------------------
__global__ __launch_bounds__(64) void gnn_scan2_kernel(
    int* __restrict__ bsums, int nb)
{
    const int lane = threadIdx.x;
    const int val = (lane < nb) ? bsums[lane] : 0;
    int incl = val;
    #pragma unroll
    for (int off = 1; off < 64; off <<= 1) {
        const int t = __shfl_up(incl, off);
        if (lane >= off) incl += t;
    }
    if (lane < nb) bsums[lane] = incl - val;
}

// ---------------------------------------------------------------------------
// K2d: phase 3 — add block base; emit offsets[n+1] and cursor copy.
// ---------------------------------------------------------------------------
__global__ __launch_bounds__(256) void gnn_scan3_kernel(
    const int* __restrict__ scanbuf, const int* __restrict__ bsums,
    int* __restrict__ offsets, int* __restrict__ cursor, int n, int total)
{
    const int i = blockIdx.x * blockDim.x + threadIdx.x;
    if (i < n) {
        const int o = scanbuf[i] + bsums[i / SCAN_EPB];
        offsets[i] = o;
        cursor[i]  = o;
    }
    if (i == 0) offsets[n] = total;
}

// ---------------------------------------------------------------------------
// K2e: per-chunk starting row.
// ---------------------------------------------------------------------------
__global__ __launch_bounds__(256) void gnn_chunk_heads_kernel(
    const int* __restrict__ offsets, int* __restrict__ first_row, int n_nodes)
{
    const int r = blockIdx.x * blockDim.x + threadIdx.x;
    if (r >= n_nodes) return;
    const int lo = offsets[r], hi = offsets[r + 1];
    if (lo == hi) return;
    const int c0 = (lo + EPW - 1) / EPW;
    const int c1 = (hi - 1) / EPW;
    for (int c = c0; c <= c1; ++c) first_row[c] = r;
}

// ---------------------------------------------------------------------------
// K2f: scatter edges into row-sorted (col, val) pairs
// ---------------------------------------------------------------------------
__global__ __launch_bounds__(256) void gnn_scatter_pairs_kernel(
    const int* __restrict__ edge_rows, const int* __restrict__ edge_cols,
    const float* __restrict__ adj_vals, int* __restrict__ cursor,
    int2* __restrict__ pairs, int n_edges)
{
    const int e = blockIdx.x * blockDim.x + threadIdx.x;
    if (e >= n_edges) return;
    const int r = edge_rows[e];
    const int pos = atomicAdd(&cursor[r], 1);
    pairs[pos] = make_int2(edge_cols[e], __float_as_int(adj_vals[e]));
}

// ---------------------------------------------------------------------------
// K3: segmented SpMM reduce. One wave per EPW-edge chunk; lanes = 4 edges x
// 16 dim-quads. 8 B bf16 h-gathers; row boundaries from a lane-resident
// offsets window (shfl broadcast, no dependent global loads). Interior rows:
// float4 store; chunk-spanning rows: fp32 atomics (out pre-zeroed).
// ---------------------------------------------------------------------------
__global__ __launch_bounds__(256) void gnn_reduce_kernel(
    const __hip_bfloat16* __restrict__ hb, const int* __restrict__ offsets,
    const int2* __restrict__ pairs, const int* __restrict__ first_row,
    float* __restrict__ out, int n_edges, int n_nodes)
{
    const int lane = threadIdx.x & 63;
    const int wid  = blockIdx.x * 4 + (threadIdx.x >> 6);
    const int nchunk = (n_edges + EPW - 1) / EPW;
    if (wid >= nchunk) return;

    const int cs = wid * EPW;
    const int ce = (cs + EPW < n_edges) ? cs + EPW : n_edges;
    const int quarter = lane >> 4;   // which of 4 edges per step
    const int d4 = lane & 15;        // 4-dim group (8 B of bf16)

    int rbase = first_row[wid];
    int wo_i = rbase + lane;
    int woff = offsets[(wo_i < n_nodes + 1) ? wo_i : n_nodes];
    int ri = 0;

    const unsigned short* hbs = reinterpret_cast<const unsigned short*>(hb);
    int pos = cs;

    while (pos < ce) {
        // advance to the row containing pos (register window + shfl)
        int end = __shfl(woff, ri + 1);
        while (end <= pos) {
            ++ri;
            if (ri >= 63) {  // slide the window (rare)
                rbase += 63;
                wo_i = rbase + lane;
                woff = offsets[(wo_i < n_nodes + 1) ? wo_i : n_nodes];
                ri = 0;
            }
            end = __shfl(woff, ri + 1);
        }
        const int rstart  = __shfl(woff, ri);
        const int se_full = end;
        const int se = (se_full < ce) ? se_full : ce;
        const int r = rbase + ri;

        float a0 = 0.f, a1 = 0.f, a2 = 0.f, a3 = 0.f;
        int idx0 = pos + quarter;
        int2 pr = pairs[(idx0 < se) ? idx0 : pos];
        for (int p = pos; p < se; p += 4) {
            const int2 cur = pr;
            const bool vcur = (p + quarter) < se;
            const int pn = p + 4;
            if (pn < se) {
                const int idxn = pn + quarter;
                pr = pairs[(idxn < se) ? idxn : pn];
            }
            const float a = vcur ? __int_as_float(cur.y) : 0.f;
            const uint2 hv = *reinterpret_cast<const uint2*>(
                hbs + (size_t)cur.x * DIM_OUT + d4 * 4);
            a0 += a * __uint_as_float(hv.x << 16);
            a1 += a * __uint_as_float(hv.x & 0xffff0000u);
            a2 += a * __uint_as_float(hv.y << 16);
            a3 += a * __uint_as_float(hv.y & 0xffff0000u);
        }

        // combine across the 4 edge-quarters
        a0 += __shfl_xor(a0, 16); a0 += __shfl_xor(a0, 32);
        a1 += __shfl_xor(a1, 16); a1 += __shfl_xor(a1, 32);
        a2 += __shfl_xor(a2, 16); a2 += __shfl_xor(a2, 32);
        a3 += __shfl_xor(a3, 16); a3 += __shfl_xor(a3, 32);

        const bool spans = (rstart < cs) || (se_full > ce);
        if (lane < 16) {
            float* po = out + (size_t)r * DIM_OUT + d4 * 4;
            if (spans) {
                atomicAdd(po + 0, a0);
                atomicAdd(po + 1, a1);
                atomicAdd(po + 2, a2);
                atomicAdd(po + 3, a3);
            } else {
                *reinterpret_cast<float4*>(po) = make_float4(a0, a1, a2, a3);
            }
        }
        pos = se;
    }
}

// ---------------------------------------------------------------------------
// Fallback scatter (atomics) if ws_size too small for the sort path.
// ---------------------------------------------------------------------------
__global__ __launch_bounds__(256) void gnn_scatter_atomic_kernel(
    const __hip_bfloat16* __restrict__ hb, const int* __restrict__ edge_rows,
    const int* __restrict__ edge_cols, const float* __restrict__ adj_vals,
    float* __restrict__ out, int n_edges)
{
    const long long idx = (long long)blockIdx.x * blockDim.x + threadIdx.x;
    if (idx >= (long long)n_edges * DIM_OUT) return;
    const int e = (int)(idx >> 6);
    const int d = (int)(idx & 63);
    const float v = adj_vals[e] *
        __bfloat162float(hb[(size_t)edge_cols[e] * DIM_OUT + d]);
    atomicAdd(&out[(size_t)edge_rows[e] * DIM_OUT + d], v);
}

extern "C" void kernel_launch(void* const* d_in, const int* in_sizes, int n_in,
                              void* d_out, int out_size, void* d_ws, size_t ws_size,
                              hipStream_t stream)
{
    const float* x         = (const float*)d_in[0];
    const float* W         = (const float*)d_in[1];
    const int*   edge_rows = (const int*)d_in[2];
    const int*   edge_cols = (const int*)d_in[3];
    const float* adj_vals  = (const float*)d_in[4];
    float*       out       = (float*)d_out;

    const int n_nodes = in_sizes[0] / DIM_IN;
    const int n_edges = in_sizes[2];
    const int nchunk  = (n_edges + EPW - 1) / EPW;
    const int nsb     = (n_nodes + SCAN_EPB - 1) / SCAN_EPB;  // scan blocks

    // workspace layout
    char* ws = (char*)d_ws;
    size_t off = 0;
    __hip_bfloat16* hb = (__hip_bfloat16*)(ws + off);
    off = align256(off + (size_t)n_nodes * DIM_OUT * 2);
    int* counts    = (int*)(ws + off); off = align256(off + (size_t)n_nodes * 4);
    int* scanbuf   = (int*)(ws + off); off = align256(off + (size_t)n_nodes * 4);
    int* bsums     = (int*)(ws + off); off = align256(off + (size_t)nsb * 4);
    int* offsets   = (int*)(ws + off); off = align256(off + ((size_t)n_nodes + 1) * 4);
    int* cursor    = (int*)(ws + off); off = align256(off + (size_t)n_nodes * 4);
    int* first_row = (int*)(ws + off); off = align256(off + (size_t)nchunk * 4);
    int2* pairs    = (int2*)(ws + off); off = align256(off + (size_t)n_edges * 8);
    const bool use_sort = (off <= ws_size) && (nsb <= 64);

    // K1: MFMA dense transform
    {
        const int ntiles = (n_nodes + 15) / 16;
        gnn_gemm_mfma_kernel<<<(ntiles + 3) / 4, 256, 0, stream>>>(x, W, hb, n_nodes);
    }

    if (use_sort) {
        hipMemsetAsync(counts, 0, (size_t)n_nodes * 4, stream);
        hipMemsetAsync(d_out, 0, (size_t)out_size * sizeof(float), stream);
        gnn_hist_kernel<<<(n_edges + 255) / 256, 256, 0, stream>>>(
            edge_rows, counts, n_edges);
        gnn_scan1_kernel<<<nsb, 256, 0, stream>>>(counts, scanbuf, bsums, n_nodes);
        gnn_scan2_kernel<<<1, 64, 0, stream>>>(bsums, nsb);
        gnn_scan3_kernel<<<(n_nodes + 255) / 256, 256, 0, stream>>>(
            scanbuf, bsums, offsets, cursor, n_nodes, n_edges);
        gnn_chunk_heads_kernel<<<(n_nodes + 255) / 256, 256, 0, stream>>>(
            offsets, first_row, n_nodes);
        gnn_scatter_pairs_kernel<<<(n_edges + 255) / 256, 256, 0, stream>>>(
            edge_rows, edge_cols, adj_vals, cursor, pairs, n_edges);
        gnn_reduce_kernel<<<(nchunk + 3) / 4, 256, 0, stream>>>(
            hb, offsets, pairs, first_row, out, n_edges, n_nodes);
    } else {
        hipMemsetAsync(d_out, 0, (size_t)out_size * sizeof(float), stream);
        const long long total = (long long)n_edges * DIM_OUT;
        gnn_scatter_atomic_kernel<<<(int)((total + 255) / 256), 256, 0, stream>>>(
            hb, edge_rows, edge_cols, adj_vals, out, n_edges);
    }
}